// Round 6
// baseline (321.287 us; speedup 1.0000x reference)
//
#include <hip/hip_runtime.h>
#include <math.h>

#define NROWS 65536
#define DDIM  64
#define KCB   1024
#define CHUNK 64                 // codes staged in LDS per step
#define NCHUNK (KCB / CHUNK)     // 16
#define CHUNK_FLOATS (CHUNK * DDIM)  // 4096 floats = 16 KB

// ---------------------------------------------------------------------------
// Single fused kernel. Block = 256 threads = 4 waves, owns 64 rows
// (lane l of every wave handles row block*64+l).
//
// History:
//  R4: SMEM W path, 229 us — latency-bound (102-SGPR budget can't
//      double-buffer 256 B rows). VALUBusy is a gfx94x SIMD-16 formula ->
//      reported busy ~2x real on gfx950; real issue was already ~60 us.
//  R5: this LDS-stream structure with __launch_bounds__(256,4): allocator
//      clamped to VGPR=64 and SPILLED xv[64] to scratch — WRITE_SIZE 173 MB
//      (vs 16.6 MB algorithmic) was the tell. 229 us, scratch-bound.
//  R6: same structure, (256,2): xv stays in VGPRs (~100), 4 waves/SIMD,
//      2 blocks/CU. Per code-pair: 32 broadcast ds_read_b128 (~128 cyc,
//      conflict-free) vs 256 cyc FMA issue -> VALU-bound.
//
// Numerics (validated absmax 0 in R1/R3/R4/R5 — DO NOT change op order):
//   C2 = numpy pairwise sum (8 accs); L2 same; CL = sequential k-ascending
//   fp32 FMA chain; dist = (L2 - 2*CL) + C2 with explicit _rn ops.
// Tie-break: in-thread j ascending with strict <; cross-wave combine is
// lexicographic (dist, j) — exact first-index semantics (equal np-rounded
// distances are bit-identical floats here).
// ---------------------------------------------------------------------------
__global__ void __launch_bounds__(256, 2)
vq_fused_kernel(const float* __restrict__ x, const float* __restrict__ W,
                float* __restrict__ outq, float* __restrict__ outi) {
    __shared__ float wchunk[CHUNK_FLOATS];   // 16 KB staged W chunk
    __shared__ float c2s[KCB];               // 4 KB
    __shared__ float s_bd[4][64];
    __shared__ int   s_bi[4][64];

    const int tid  = threadIdx.x;
    const int lane = tid & 63;
    const int s    = __builtin_amdgcn_readfirstlane(tid >> 6);
    const int row  = blockIdx.x * 64 + lane;

    // ---- load this row of x into registers (16 x float4) ----
    const float* xr = x + (size_t)row * DDIM;
    float xv[64];
#pragma unroll
    for (int k = 0; k < 64; k += 4) {
        float4 v = *(const float4*)(xr + k);
        xv[k] = v.x; xv[k + 1] = v.y; xv[k + 2] = v.z; xv[k + 3] = v.w;
    }

    // ---- Phase 0: C2 into LDS, exact numpy pairwise sum (n=64: 8 accs) ----
    {
        const int jbase = tid * 4;           // 256 threads * 4 codes = 1024
#pragma unroll
        for (int c = 0; c < 4; ++c) {
            const float* w = W + (size_t)(jbase + c) * DDIM;
            float r[8];
#pragma unroll
            for (int m = 0; m < 8; ++m) r[m] = __fmul_rn(w[m], w[m]);
#pragma unroll
            for (int i = 8; i < 64; i += 8) {
#pragma unroll
                for (int m = 0; m < 8; ++m)
                    r[m] = __fadd_rn(r[m], __fmul_rn(w[i + m], w[i + m]));
            }
            c2s[jbase + c] = __fadd_rn(
                __fadd_rn(__fadd_rn(r[0], r[1]), __fadd_rn(r[2], r[3])),
                __fadd_rn(__fadd_rn(r[4], r[5]), __fadd_rn(r[6], r[7])));
        }
    }

    // ---- L2 = numpy pairwise sum of x*x ----
    float r[8];
#pragma unroll
    for (int m = 0; m < 8; ++m) r[m] = __fmul_rn(xv[m], xv[m]);
#pragma unroll
    for (int i = 8; i < 64; i += 8) {
#pragma unroll
        for (int m = 0; m < 8; ++m)
            r[m] = __fadd_rn(r[m], __fmul_rn(xv[i + m], xv[i + m]));
    }
    const float L2 = __fadd_rn(
        __fadd_rn(__fadd_rn(r[0], r[1]), __fadd_rn(r[2], r[3])),
        __fadd_rn(__fadd_rn(r[4], r[5]), __fadd_rn(r[6], r[7])));

    // ---- main loop: stream W chunks through LDS with register prefetch ----
    // Each thread copies 64 B x 4 of the 16 KB chunk: float4 at
    // float-offset tid*4 + n*1024 (coalesced global, contiguous ds_write).
    float best = INFINITY;
    int   bidx = 0;

    float4 pf[4];
#pragma unroll
    for (int n = 0; n < 4; ++n)
        pf[n] = *(const float4*)(W + (size_t)n * 1024 + tid * 4);

    for (int c = 0; c < NCHUNK; ++c) {
        __syncthreads();   // previous chunk fully consumed (no-op at c=0)
#pragma unroll
        for (int n = 0; n < 4; ++n)
            *(float4*)(&wchunk[n * 1024 + tid * 4]) = pf[n];
        if (c < NCHUNK - 1) {
#pragma unroll
            for (int n = 0; n < 4; ++n)
                pf[n] = *(const float4*)(W + (size_t)(c + 1) * CHUNK_FLOATS
                                           + (size_t)n * 1024 + tid * 4);
        }
        __syncthreads();   // chunk staged (also covers Phase-0 c2s at c=0)

        // wave s consumes codes [c*64 + s*16, +16) as 8 interleaved pairs
        const int jg0 = c * CHUNK + s * 16;
        const float* wl = &wchunk[s * 16 * DDIM];
        for (int p = 0; p < 8; ++p) {
            const float* w0 = wl + (size_t)(2 * p) * DDIM;  // wave-uniform
            float acc0 = 0.0f, acc1 = 0.0f;
#pragma unroll
            for (int k = 0; k < 64; ++k) {
                acc0 = __builtin_fmaf(xv[k], w0[k], acc0);
                acc1 = __builtin_fmaf(xv[k], w0[DDIM + k], acc1);
            }
            const int j = jg0 + 2 * p;
            const float d0 = __fadd_rn(__fsub_rn(L2, __fmul_rn(2.0f, acc0)), c2s[j]);
            const float d1 = __fadd_rn(__fsub_rn(L2, __fmul_rn(2.0f, acc1)), c2s[j + 1]);
            if (d0 < best) { best = d0; bidx = j; }      // ascending j in-thread
            if (d1 < best) { best = d1; bidx = j + 1; }
        }
    }

    s_bd[s][lane] = best;
    s_bi[s][lane] = bidx;
    __syncthreads();

    // ---- combine: lexicographic (dist, j) — exact first-index semantics ----
    if (s == 0) {
        float b  = s_bd[0][lane];
        int   bi = s_bi[0][lane];
#pragma unroll
        for (int t = 1; t < 4; ++t) {
            const float d = s_bd[t][lane];
            const int   i = s_bi[t][lane];
            if (d < b || (d == b && i < bi)) { b = d; bi = i; }
        }
        outi[row] = (float)bi;   // harness reads indices as fp32
        s_bi[0][lane] = bi;      // broadcast for gather
    }
    __syncthreads();

    // ---- fused gather: 4 threads per row, 16 floats (4 x float4) each ----
    {
        const int rloc  = tid >> 2;           // 0..63
        const int quart = tid & 3;            // 0..3
        const int j     = s_bi[0][rloc];
        const float* src = W + (size_t)j * DDIM + quart * 16;
        float* dst = outq + ((size_t)blockIdx.x * 64 + rloc) * DDIM + quart * 16;
#pragma unroll
        for (int u = 0; u < 4; ++u)
            *(float4*)(dst + 4 * u) = *(const float4*)(src + 4 * u);
    }
}

extern "C" void kernel_launch(void* const* d_in, const int* in_sizes, int n_in,
                              void* d_out, int out_size, void* d_ws, size_t ws_size,
                              hipStream_t stream) {
    const float* x = (const float*)d_in[0];
    const float* W = (const float*)d_in[1];

    float* outq = (float*)d_out;                        // N*D quantized
    float* outi = (float*)d_out + (size_t)NROWS * DDIM; // N indices as float

    hipLaunchKernelGGL(vq_fused_kernel, dim3(NROWS / 64), dim3(256), 0, stream,
                       x, W, outq, outi);
}